// Round 22
// baseline (112.099 us; speedup 1.0000x reference)
//
#include <hip/hip_runtime.h>
#include <hip/hip_bf16.h>

#define CCH   512
#define BATCH 8
#define NPOS  1024
#define MQKV  1536
#define EPS   1e-5f
#define LOG2E 1.4426950408889634f

typedef __attribute__((ext_vector_type(4))) float f32x4;
typedef __attribute__((ext_vector_type(16))) float f32x16;
typedef __attribute__((ext_vector_type(8))) __bf16 bf16x8;
typedef __attribute__((ext_vector_type(8))) unsigned short u16x8;
typedef __attribute__((ext_vector_type(4))) unsigned short u16x4;

__device__ inline unsigned short f2bf(float f) {
  __hip_bfloat16 h = __float2bfloat16(f);
  return __builtin_bit_cast(unsigned short, h);
}
__device__ inline float bf2f(unsigned short u) {
  return __bfloat162float(__builtin_bit_cast(__hip_bfloat16, u));
}

// LDS xor-swizzle for [row][64] ushort tiles (128B rows): maps col-slice reads across banks.
__device__ inline int sw(int row, int col) { return row * 64 + (col ^ ((row & 7) << 3)); }
// LDS xor-swizzle for [row][32] ushort tiles (64B rows): chunk ^= (row ^ row>>2)&3.
__device__ inline int sw32(int row, int lh) {
  return row * 32 + ((lh ^ ((row ^ (row >> 2)) & 3)) << 3);
}

// 16B async global->LDS. LDS dest is wave-uniform; HW scatters lane i at dst + i*16B.
__device__ inline void gload16(const void* g, void* l) {
  __builtin_amdgcn_global_load_lds((const __attribute__((address_space(1))) void*)g,
                                   (__attribute__((address_space(3))) void*)l, 16, 0, 0);
}

// counted-wait barrier (T4): leave the newest N vmem loads in flight; drain LDS ops, join.
#define CBAR(N) do {                                              \
    asm volatile("s_waitcnt vmcnt(" #N ")" ::: "memory");         \
    asm volatile("s_waitcnt lgkmcnt(0)" ::: "memory");            \
    __builtin_amdgcn_s_barrier();                                 \
  } while (0)

// ---------------- 1. setup: prep_weights (vectorized) | layernorm | bias_expand ----------------
// biasP layout is IDENTITY [h][i][j].
__global__ __launch_bounds__(256) void setup_kernel(
    const float* __restrict__ wq, const float* __restrict__ wo,
    unsigned short* __restrict__ wqb, unsigned short* __restrict__ wob,
    const float* __restrict__ x, const float* __restrict__ gamma,
    unsigned short* __restrict__ xnT,
    const float* __restrict__ table, unsigned short* __restrict__ biasP) {
  __shared__ float red[4][32][2];
  __shared__ float gsh[512];
  __shared__ unsigned short obuf[32 * 520];
  int bid = blockIdx.x, tid = threadIdx.x;

  if (bid >= 640) {
    int base = ((bid - 640) * 256 + tid) * 8;    // 8M total / 8 per thread
    int h = base >> 20;
    int i = (base >> 10) & 1023;
    int j0 = base & 1023;
    int ib = i >> 5, il = i & 31;
    u16x8 outv;
    #pragma unroll
    for (int e = 0; e < 8; ++e) {
      int j = j0 + e;
      int dy = ib - (j >> 5) + 31;
      int dx = il - (j & 31) + 31;
      outv[e] = f2bf(table[h * 3969 + dy * 63 + dx]);
    }
    *(u16x8*)&biasP[base] = outv;
    return;
  }

  if (bid < 384) {
    int base = bid * 2048 + tid * 8;
    float sc = (base < 512 * CCH) ? (0.125f * LOG2E) : 1.0f;
    f32x4 v0 = *(const f32x4*)&wq[base];
    f32x4 v1 = *(const f32x4*)&wq[base + 4];
    u16x8 outv;
    #pragma unroll
    for (int e = 0; e < 4; ++e) outv[e] = f2bf(v0[e] * sc);
    #pragma unroll
    for (int e = 0; e < 4; ++e) outv[4 + e] = f2bf(v1[e] * sc);
    *(u16x8*)&wqb[base] = outv;
    if (base < CCH * CCH) {
      f32x4 w0v = *(const f32x4*)&wo[base];
      f32x4 w1v = *(const f32x4*)&wo[base + 4];
      u16x8 ov;
      #pragma unroll
      for (int e = 0; e < 4; ++e) ov[e] = f2bf(w0v[e]);
      #pragma unroll
      for (int e = 0; e < 4; ++e) ov[4 + e] = f2bf(w1v[e]);
      *(u16x8*)&wob[base] = ov;
    }
  } else {
    int blk = bid - 384;
    int b = blk >> 5, p0 = (blk & 31) * 32;
    int pl = tid & 31, wv = tid >> 6, cg = tid >> 5;
    gsh[tid] = gamma[tid];
    gsh[tid + 256] = gamma[tid + 256];
    const float* xp = x + (size_t)b * CCH * NPOS + p0 + pl;
    float vals[64];
    float s1 = 0.f, s2 = 0.f;
    #pragma unroll
    for (int j = 0; j < 64; ++j) {
      float v = xp[(size_t)(cg + 8 * j) * NPOS];
      vals[j] = v; s1 += v; s2 += v * v;
    }
    s1 += __shfl_xor(s1, 32, 64); s2 += __shfl_xor(s2, 32, 64);
    if ((tid & 63) < 32) { red[wv][pl][0] = s1; red[wv][pl][1] = s2; }
    __syncthreads();
    float t1 = 0.f, t2 = 0.f;
    #pragma unroll
    for (int w2i = 0; w2i < 4; ++w2i) { t1 += red[w2i][pl][0]; t2 += red[w2i][pl][1]; }
    float mean = t1 * (1.f / 512.f);
    float var = t2 * (1.f / 512.f) - mean * mean;
    float rstd = rsqrtf(var + EPS);
    #pragma unroll
    for (int j = 0; j < 64; ++j) {
      int c = cg + 8 * j;
      obuf[pl * 520 + c] = f2bf((vals[j] - mean) * rstd * gsh[c]);
    }
    __syncthreads();
    unsigned short* orow = xnT + ((size_t)b * NPOS + p0) * 512;
    #pragma unroll
    for (int i = 0; i < 8; ++i) {
      int c2 = tid + i * 256;
      int pp = c2 >> 6, ch = c2 & 63;
      *(u16x8*)&orow[(size_t)pp * 512 + ch * 8] = *(const u16x8*)&obuf[pp * 520 + ch * 8];
    }
  }
}

// ---------------- 2. CPB table with LDS-cached w1/w2 ----------------
__global__ __launch_bounds__(256) void cpb_kernel(
    const float* __restrict__ w0, const float* __restrict__ b0,
    const float* __restrict__ w1, const float* __restrict__ b1,
    const float* __restrict__ w2, const float* __restrict__ b2,
    float* __restrict__ table) {
  __shared__ float w1s[128 * 129];
  __shared__ float w2s[8 * 128];
  __shared__ float sh1[2][128];
  __shared__ float sh2[2][128];
  int tid = threadIdx.x;
  #pragma unroll
  for (int i = 0; i < 64; ++i) {
    int idx = i * 256 + tid;
    w1s[(idx >> 7) * 129 + (idx & 127)] = w1[idx];
  }
  #pragma unroll
  for (int i = 0; i < 4; ++i) {
    int idx = i * 256 + tid;
    w2s[idx] = w2[idx];
  }
  int sub = tid >> 7, t = tid & 127;
  float w00 = w0[t * 2 + 0], w01 = w0[t * 2 + 1], bb0 = b0[t], bb1 = b1[t];
  int hh = t >> 4, k16 = t & 15;
  float b2h = b2[hh];
  __syncthreads();

  #pragma unroll 1
  for (int pass = 0; pass < 8; ++pass) {
    int d0 = (blockIdx.x * 8 + pass) * 2 + sub;
    bool ok = d0 < 3969;
    int d0c = ok ? d0 : 0;
    int dy = d0c / 63 - 31, dx = d0c % 63 - 31;
    float r0 = (dy > 0 ? 1.f : (dy < 0 ? -1.f : 0.f)) * logf(fabsf((float)dy) + 1.f);
    float r1 = (dx > 0 ? 1.f : (dx < 0 ? -1.f : 0.f)) * logf(fabsf((float)dx) + 1.f);
    float h0 = r0 * w00 + r1 * w01 + bb0;
    sh1[sub][t] = (h0 >= 0.f) ? h0 : 0.1f * h0;
    __syncthreads();
    float a = bb1;
    #pragma unroll 8
    for (int c = 0; c < 128; ++c) a += sh1[sub][c] * w1s[t * 129 + c];
    sh2[sub][t] = (a >= 0.f) ? a : 0.1f * a;
    __syncthreads();
    float o = 0.f;
    #pragma unroll
    for (int c = 0; c < 8; ++c) o += sh2[sub][k16 * 8 + c] * w2s[hh * 128 + k16 * 8 + c];
    #pragma unroll
    for (int mm = 1; mm < 16; mm <<= 1) o += __shfl_xor(o, mm, 64);
    if (k16 == 0 && ok) table[hh * 3969 + d0] = (o + b2h) * LOG2E;
    __syncthreads();
  }
}

// ---------------- 3. qkv GEMM: BK=32 TRIPLE-buffered counted-vmcnt pipeline ----------------
__global__ __launch_bounds__(256) void gemm_qkv(const unsigned short* __restrict__ Ag,
                                                const unsigned short* __restrict__ Bg,
                                                unsigned short* __restrict__ qT,
                                                unsigned short* __restrict__ kT,
                                                unsigned short* __restrict__ vB) {
  __shared__ unsigned short smem[24576];
  int tid = threadIdx.x;
  int by = blockIdx.y;
  int m0 = by * 128, nn0 = blockIdx.x * 128;
  int wave = tid >> 6, lane = tid & 63;
  int wm = wave >> 1, wn = wave & 1;
  int l16 = lane & 15, lh = lane >> 4;
  int r4 = lane >> 2, c4 = lane & 3;
  int csw = ((c4 ^ (r4 & 3) ^ ((lane >> 4) & 3))) << 3;
  f32x4 acc[4][4];
  #pragma unroll
  for (int it = 0; it < 4; ++it)
    #pragma unroll
    for (int jt = 0; jt < 4; ++jt) acc[it][jt] = (f32x4){0.f, 0.f, 0.f, 0.f};

  #define GSTAGE(bsel, k0) do {                                                               \
    _Pragma("unroll")                                                                         \
    for (int i_ = 0; i_ < 2; ++i_) {                                                          \
      int grp_ = wave * 2 + i_;                                                               \
      int row_ = grp_ * 16 + r4;                                                              \
      gload16(&Ag[(size_t)(m0 + row_) * 512 + (k0) + csw], smem + (bsel) * 4096 + grp_ * 512);\
      gload16(&Bg[(size_t)(nn0 + row_) * 512 + (k0) + csw],                                   \
              smem + 12288 + (bsel) * 4096 + grp_ * 512);                                     \
    }                                                                                         \
  } while (0)

  GSTAGE(0, 0);
  GSTAGE(1, 32);
  asm volatile("s_waitcnt vmcnt(4)" ::: "memory");
  __builtin_amdgcn_s_barrier();
  int cur = 0;
  #pragma unroll 1
  for (int k = 0; k < 16; ++k) {
    int stg = (cur == 0) ? 2 : cur - 1;
    if (k < 14) GSTAGE(stg, (k + 2) * 32);
    const unsigned short* As = smem + cur * 4096;
    const unsigned short* Bs = smem + 12288 + cur * 4096;
    bf16x8 a[4], b[4];
    #pragma unroll
    for (int it = 0; it < 4; ++it) a[it] = *(const bf16x8*)&As[sw32(wm * 64 + it * 16 + l16, lh)];
    #pragma unroll
    for (int jt = 0; jt < 4; ++jt) b[jt] = *(const bf16x8*)&Bs[sw32(wn * 64 + jt * 16 + l16, lh)];
    __builtin_amdgcn_s_setprio(1);
    #pragma unroll
    for (int it = 0; it < 4; ++it)
      #pragma unroll
      for (int jt = 0; jt < 4; ++jt)
        acc[it][jt] = __builtin_amdgcn_mfma_f32_16x16x32_bf16(a[it], b[jt], acc[it][jt], 0, 0, 0);
    __builtin_amdgcn_s_setprio(0);
    if (k < 14) CBAR(4); else CBAR(0);
    cur = (cur == 2) ? 0 : cur + 1;
  }

  // ---- LDS-bounced coalesced epilogue ----
  int sel = by >> 2;
  int hh0 = (by & 3) * 2;
  int bb = nn0 >> 10, p0 = nn0 & 1023;
  unsigned short* Cs = smem;
  if (sel < 2) {
    #pragma unroll
    for (int it = 0; it < 4; ++it)
      #pragma unroll
      for (int jt = 0; jt < 4; ++jt) {
        int nnl = wn * 64 + jt * 16 + l16;
        int mb = wm * 64 + it * 16 + lh * 4;
        #pragma unroll
        for (int r = 0; r < 4; ++r)
          Cs[nnl * 128 + ((mb + r) ^ ((nnl & 7) << 4))] = f2bf(acc[it][jt][r]);
      }
    __syncthreads();
    unsigned short* dst = (sel == 0) ? qT : kT;
    #pragma unroll
    for (int i = 0; i < 8; ++i) {
      int c = tid + i * 256;
      int hl = c >> 10, p = (c >> 3) & 127, ch = c & 7;
      int mb = hl * 64 + ch * 8;
      u16x8 val = *(u16x8*)&Cs[p * 128 + (mb ^ ((p & 7) << 4))];
      int bh = bb * 8 + hh0 + hl;
      *(u16x8*)&dst[((size_t)bh * 1024 + p0 + p) * 64 + ch * 8] = val;
    }
  } else {
    #pragma unroll
    for (int it = 0; it < 4; ++it)
      #pragma unroll
      for (int jt = 0; jt < 4; ++jt) {
        int nnl = wn * 64 + jt * 16 + l16;
        int mb = wm * 64 + it * 16 + lh * 4;
        #pragma unroll
        for (int r = 0; r < 4; ++r)
          Cs[(mb + r) * 128 + (nnl ^ (((mb + r) & 7) << 4))] = f2bf(acc[it][jt][r]);
      }
    __syncthreads();
    #pragma unroll
    for (int i = 0; i < 8; ++i) {
      int c = tid + i * 256;
      int mloc = c >> 4, ch = c & 15;
      u16x8 val = *(u16x8*)&Cs[mloc * 128 + ((ch * 8) ^ ((mloc & 7) << 4))];
      int d = mloc & 63, hl = mloc >> 6;
      int bh = bb * 8 + hh0 + hl;
      *(u16x8*)&vB[((size_t)bh * 64 + d) * 1024 + p0 + ch * 8] = val;
    }
  }
}

// ---------------- 4. out GEMM: 64x128 tiles, TRIPLE-buffered counted-vmcnt ----------------
__global__ __launch_bounds__(256) void gemm_out(const unsigned short* __restrict__ Ag,
                                                const unsigned short* __restrict__ Bg,
                                                const float* __restrict__ xres,
                                                float* __restrict__ yout) {
  __shared__ unsigned short smem[18432];
  int tid = threadIdx.x;
  int m0 = blockIdx.y * 64, nn0 = blockIdx.x * 128;
  int wave = tid >> 6, lane = tid & 63;
  int wm = wave >> 1, wn = wave & 1;
  int l16 = lane & 15, lh = lane >> 4;
  int r4 = lane >> 2, c4 = lane & 3;
  int csw = ((c4 ^ (r4 & 3) ^ ((lane >> 4) & 3))) << 3;
  f32x4 acc[2][4];
  #pragma unroll
  for (int it = 0; it < 2; ++it)
    #pragma unroll
    for (int jt = 0; jt < 4; ++jt) acc[it][jt] = (f32x4){0.f, 0.f, 0.f, 0.f};

  #define OSTAGE(bsel, k0) do {                                                               \
    {                                                                                         \
      int row_ = wave * 16 + r4;                                                              \
      gload16(&Ag[(size_t)(m0 + row_) * 512 + (k0) + csw],                                    \
              smem + (bsel) * 2048 + wave * 512);                                             \
    }                                                                                         \
    _Pragma("unroll")                                                                         \
    for (int i_ = 0; i_ < 2; ++i_) {                                                          \
      int grp_ = wave * 2 + i_;                                                               \
      int row_ = grp_ * 16 + r4;                                                              \
      gload16(&Bg[(size_t)(nn0 + row_) * 512 + (k0) + csw],                                   \
              smem + 6144 + (bsel) * 4096 + grp_ * 512);                                      \
    }                                                                                         \
  } while (0)

  OSTAGE(0, 0);
  OSTAGE(1, 32);
  asm volatile("s_waitcnt vmcnt(3)" ::: "memory");
  __builtin_amdgcn_s_barrier();
  int cur = 0;
  #pragma unroll 1
  for (int k = 0; k < 16; ++k) {
    int stg = (cur == 0) ? 2 : cur - 1;
    if (k < 14) OSTAGE(stg, (k + 2) * 32);
    const unsigned short* As = smem + cur * 2048;
    const unsigned short* Bs = smem + 6144 + cur * 4096;
    bf16x8 a[2], b[4];
    #pragma unroll
    for (int it = 0; it < 2; ++it) a[it] = *(const bf16x8*)&As[sw32(wm * 32 + it * 16 + l16, lh)];
    #pragma unroll
    for (int jt = 0; jt < 4; ++jt) b[jt] = *(const bf16x8*)&Bs[sw32(wn * 64 + jt * 16 + l16, lh)];
    __builtin_amdgcn_s_setprio(1);
    #pragma unroll
    for (int it = 0; it < 2; ++it)
      #pragma unroll
      for (int jt = 0; jt < 4; ++jt)
        acc[it][jt] = __builtin_amdgcn_mfma_f32_16x16x32_bf16(a[it], b[jt], acc[it][jt], 0, 0, 0);
    __builtin_amdgcn_s_setprio(0);
    if (k < 14) CBAR(3); else CBAR(0);
    cur = (cur == 2) ? 0 : cur + 1;
  }

  #pragma unroll
  for (int it = 0; it < 2; ++it) {
    int mbase = m0 + wm * 32 + it * 16 + lh * 4;
    #pragma unroll
    for (int jt = 0; jt < 4; ++jt) {
      int nn = nn0 + wn * 64 + jt * 16 + l16;
      int bb = nn >> 10, p = nn & 1023;
      #pragma unroll
      for (int r = 0; r < 4; ++r) {
        size_t addr = ((size_t)bb * 512 + mbase + r) * 1024 + p;
        yout[addr] = acc[it][jt][r] + xres[addr];
      }
    }
  }
}

// ---------------- 5. flash attention: 32x32 MFMA, 4 waves x 32 q-rows ----------------
// S^T = K·Q^T (A=K LDS, B=Q^T regs): lane owns q=lane&31, j rows via reg pattern.
// P stored [q][j] with consecutive-j u16x4 writes; PV: O = P·V (A=P LDS b128, B=V b128).
// Denominator = ones-MFMA reusing pa frags. Triple-buffered K/V, bias regs 1 tile ahead.
__global__ __launch_bounds__(256) void attn_kernel(const unsigned short* __restrict__ qT,
                                                   const unsigned short* __restrict__ kT,
                                                   const unsigned short* __restrict__ vB,
                                                   const unsigned short* __restrict__ biasP,
                                                   unsigned short* __restrict__ attnout) {
  __shared__ unsigned short Kbuf[3][64 * 64];
  __shared__ unsigned short Vbuf[3][64 * 64];
  __shared__ unsigned short Ps[4][32 * 64];
  int tid = threadIdx.x;
  int bh = blockIdx.x;               // bh-fastest: XCD = bh%8
  int i0 = blockIdx.y * 128;
  int hh = bh & 7, bb = bh >> 3;
  int w = tid >> 6, lane = tid & 63;
  int l32 = lane & 31, hi = lane >> 5;
  int rsub = lane >> 3, csub = lane & 7;
  int scsw = (csub ^ rsub) * 8;      // pre-swizzled source col (row&7 rule, both K and V)

  const unsigned short* kbase = kT + (size_t)bh * NPOS * 64;
  const unsigned short* vbase = vB + (size_t)bh * 64 * NPOS;
  int qg = i0 + w * 32 + l32;        // this lane's q row (global within bh)
  const unsigned short* bptr = biasP + ((size_t)hh * 1024 + qg) * 1024;

  // Q fragments in registers: B-operand for S^T (col=q=lane&31, k=d): qreg[s][e] = Q[q][s*16+hi*8+e]
  const unsigned short* qb = qT + ((size_t)bh * NPOS + qg) * 64;
  bf16x8 qreg[4];
  #pragma unroll
  for (int s = 0; s < 4; ++s) qreg[s] = *(const bf16x8*)&qb[s * 16 + hi * 8];

  f32x16 acc[2], den;                // O cols d = dt*32+l32; den rows q via reg pattern
  #pragma unroll
  for (int e = 0; e < 16; ++e) { acc[0][e] = 0.f; acc[1][e] = 0.f; den[e] = 0.f; }

  bf16x8 ones;
  {
    u16x8 tmp = {0x3F80, 0x3F80, 0x3F80, 0x3F80, 0x3F80, 0x3F80, 0x3F80, 0x3F80};
    ones = __builtin_bit_cast(bf16x8, tmp);
  }

  // stage tile jj: 4 waves x 2 groups each for K and V (4 vmem loads/thread)
  #define STAGE(Kd, Vd, jj) do {                                                          \
    _Pragma("unroll")                                                                     \
    for (int i_ = 0; i_ < 2; ++i_) {                                                      \
      int grp_ = w * 2 + i_;                                                              \
      gload16(&kbase[(size_t)((jj) + grp_ * 8 + rsub) * 64 + scsw], &(Kd)[grp_ * 512]);   \
      gload16(&vbase[(size_t)(grp_ * 8 + rsub) * 1024 + (jj) + scsw], &(Vd)[grp_ * 512]); \
    }                                                                                     \
  } while (0)

  // bias regs: bv[js*4+m][r] = bias[q][j0 + js*32 + 4*hi + 8*m + r]
  #define BLOAD(dst, jj) do {                                                             \
    _Pragma("unroll")                                                                     \
    for (int js_ = 0; js_ < 2; ++js_)                                                     \
      _Pragma("unroll")                                                                   \
      for (int m_ = 0; m_ < 4; ++m_)                                                      \
        dst[js_ * 4 + m_] = *(const u16x4*)&bptr[(jj) + js_ * 32 + 4 * hi + 8 * m_];      \
  } while (0)

  // prologue: stage0[4], bias0[8], stage1[4] -> retire stage0 with vmcnt(12)
  STAGE(Kbuf[0], Vbuf[0], 0);
  u16x4 bvc[8];
  BLOAD(bvc, 0);
  STAGE(Kbuf[1], Vbuf[1], 64);
  asm volatile("s_waitcnt vmcnt(12)" ::: "memory");
  __builtin_amdgcn_s_barrier();
  int cur = 0;

  #pragma unroll 1
  for (int t = 0; t < 16; ++t) {
    int j0 = t * 64;

    // bias(t+1) prefetch FIRST (older than staging in the vmcnt FIFO)
    u16x4 bvn[8];
    if (t < 15) BLOAD(bvn, j0 + 64);

    int stg = (cur == 0) ? 2 : cur - 1;              // (cur+2)%3
    if (t < 14) STAGE(Kbuf[stg], Vbuf[stg], j0 + 128);

    const unsigned short* Ks = Kbuf[cur];
    const unsigned short* Vs = Vbuf[cur];

    // ---- S^T = K·Q^T: per j-sub-tile js, 4 K-steps over d ----
    f32x16 sT[2];
    #pragma unroll
    for (int e = 0; e < 16; ++e) { sT[0][e] = 0.f; sT[1][e] = 0.f; }
    __builtin_amdgcn_s_setprio(1);
    #pragma unroll
    for (int js = 0; js < 2; ++js)
      #pragma unroll
      for (int s = 0; s < 4; ++s) {
        bf16x8 ak = *(const bf16x8*)&Ks[sw(js * 32 + l32, s * 16 + hi * 8)];
        sT[js] = __builtin_amdgcn_mfma_f32_32x32x16_bf16(ak, qreg[s], sT[js], 0, 0, 0);
      }
    __builtin_amdgcn_s_setprio(0);

    // ---- P = exp2(S + bias): lane owns q=l32; j = js*32 + 4*hi + 8*m + r ----
    #pragma unroll
    for (int js = 0; js < 2; ++js)
      #pragma unroll
      for (int m = 0; m < 4; ++m) {
        u16x4 pq;
        #pragma unroll
        for (int r = 0; r < 4; ++r)
          pq[r] = f2bf(__builtin_amdgcn_exp2f(sT[js][m * 4 + r] + bf2f(bvc[js * 4 + m][r])));
        *(u16x4*)&Ps[w][sw(l32, js * 32 + 4 * hi + 8 * m)] = pq;
      }

    // ---- PV: O += P·V (A=P row q, k j; B=V col d, k j); den += P·1 ----
    __builtin_amdgcn_s_setprio(1);
    #pragma unroll
    for (int s = 0; s < 4; ++s) {
      bf16x8 pa = *(const bf16x8*)&Ps[w][sw(l32, s * 16 + hi * 8)];
      #pragma unroll
      for (int dt = 0; dt < 2; ++dt) {
        bf16x8 vb = *(const bf16x8*)&Vs[sw(dt * 32 + l32, s * 16 + hi * 8)];
        acc[dt] = __builtin_amdgcn_mfma_f32_32x32x16_bf16(pa, vb, acc[dt], 0, 0, 0);
      }
      den = __builtin_amdgcn_mfma_f32_32x32x16_bf16(pa, ones, den, 0, 0, 0);
    }
    __builtin_amdgcn_s_setprio(0);

    // rotate bias regs (forces bias(t+1) retirement; stage(t+2) keeps floating)
    if (t < 15) {
      #pragma unroll
      for (int b_ = 0; b_ < 8; ++b_) bvc[b_] = bvn[b_];
    }

    if (t < 14) CBAR(4); else CBAR(0);
    cur = (cur == 2) ? 0 : cur + 1;
  }

  // ---- epilogue: O[q][d], q = (reg&3)+8*(reg>>2)+4*hi, d = dt*32+l32 ----
  #pragma unroll
  for (int reg = 0; reg < 16; ++reg) {
    int qrow = (reg & 3) + 8 * (reg >> 2) + 4 * hi;
    int gi = i0 + w * 32 + qrow;
    float inv = 1.f / den[reg];
    unsigned short* orow = attnout + ((size_t)bb * 1024 + gi) * 512 + hh * 64 + l32;
    orow[0]  = f2bf(acc[0][reg] * inv);
    orow[32] = f2bf(acc[1][reg] * inv);
  }
}

extern "C" void kernel_launch(void* const* d_in, const int* in_sizes, int n_in,
                              void* d_out, int out_size, void* d_ws, size_t ws_size,
                              hipStream_t stream) {
  const float* x     = (const float*)d_in[0];
  const float* gamma = (const float*)d_in[1];
  const float* w_qkv = (const float*)d_in[2];
  const float* w_out = (const float*)d_in[3];
  const float* cw0   = (const float*)d_in[4];
  const float* cb0   = (const float*)d_in[5];
  const float* cw1   = (const float*)d_in[6];
  const float* cb1   = (const float*)d_in[7];
  const float* cw2   = (const float*)d_in[8];
  const float* cb2   = (const float*)d_in[9];
  float* out = (float*)d_out;

  char* ws = (char*)d_ws;
  unsigned short* xnT   = (unsigned short*)(ws + 0);          // 8 MB
  unsigned short* wqb   = (unsigned short*)(ws + 8388608);    // 1.5 MB
  unsigned short* wob   = (unsigned short*)(ws + 9961472);    // 0.5 MB
  unsigned short* qT    = (unsigned short*)(ws + 10485760);   // 8 MB
  unsigned short* kT    = (unsigned short*)(ws + 18874368);   // 8 MB
  unsigned short* vB    = (unsigned short*)(ws + 27262976);   // 8 MB
  float*          table = (float*)(ws + 35651584);            // 128 KB
  unsigned short* biasP = (unsigned short*)(ws + 35782656);   // 16 MB
  unsigned short* aout  = (unsigned short*)(ws + 52559872);   // 8 MB

  cpb_kernel<<<256, 256, 0, stream>>>(cw0, cb0, cw1, cb1, cw2, cb2, table);
  setup_kernel<<<4736, 256, 0, stream>>>(w_qkv, w_out, wqb, wob, x, gamma, xnT, table, biasP);
  gemm_qkv<<<dim3(64, 12), 256, 0, stream>>>(wqb, xnT, qT, kT, vB);
  attn_kernel<<<dim3(64, 8), 256, 0, stream>>>(qT, kT, vB, biasP, aout);
  gemm_out<<<dim3(64, 8), 256, 0, stream>>>(wob, aout, x, out);
}

// Round 23
// 99.139 us; speedup vs baseline: 1.1307x; 1.1307x over previous
//
#include <hip/hip_runtime.h>
#include <hip/hip_bf16.h>

#define CCH   512
#define BATCH 8
#define NPOS  1024
#define MQKV  1536
#define EPS   1e-5f
#define LOG2E 1.4426950408889634f

typedef __attribute__((ext_vector_type(4))) float f32x4;
typedef __attribute__((ext_vector_type(8))) __bf16 bf16x8;
typedef __attribute__((ext_vector_type(8))) unsigned short u16x8;
typedef __attribute__((ext_vector_type(4))) unsigned short u16x4;

__device__ inline unsigned short f2bf(float f) {
  __hip_bfloat16 h = __float2bfloat16(f);
  return __builtin_bit_cast(unsigned short, h);
}
__device__ inline float bf2f(unsigned short u) {
  return __bfloat162float(__builtin_bit_cast(__hip_bfloat16, u));
}

// LDS xor-swizzle for [row][64] ushort tiles (128B rows): 2-way (free) aliasing.
__device__ inline int sw(int row, int col) { return row * 64 + (col ^ ((row & 7) << 3)); }
// K-variant: rows are read at stride 4 (row = l16*4 + jt), so swizzle on row>>2.
__device__ inline int swk(int row, int col) { return row * 64 + (col ^ (((row >> 2) & 7) << 3)); }
// LDS xor-swizzle for [row][32] ushort tiles (64B rows): chunk ^= (row ^ row>>2)&3.
__device__ inline int sw32(int row, int lh) {
  return row * 32 + ((lh ^ ((row ^ (row >> 2)) & 3)) << 3);
}

// 16B async global->LDS. LDS dest is wave-uniform; HW scatters lane i at dst + i*16B.
__device__ inline void gload16(const void* g, void* l) {
  __builtin_amdgcn_global_load_lds((const __attribute__((address_space(1))) void*)g,
                                   (__attribute__((address_space(3))) void*)l, 16, 0, 0);
}

// counted-wait barrier (T4): leave the newest N vmem loads in flight; drain LDS ops, join.
#define CBAR(N) do {                                              \
    asm volatile("s_waitcnt vmcnt(" #N ")" ::: "memory");         \
    asm volatile("s_waitcnt lgkmcnt(0)" ::: "memory");            \
    __builtin_amdgcn_s_barrier();                                 \
  } while (0)

// ---------------- 1. setup: prep_weights (vectorized) | layernorm | bias_expand ----------------
// biasP layout is IDENTITY [h][i][j].
__global__ __launch_bounds__(256) void setup_kernel(
    const float* __restrict__ wq, const float* __restrict__ wo,
    unsigned short* __restrict__ wqb, unsigned short* __restrict__ wob,
    const float* __restrict__ x, const float* __restrict__ gamma,
    unsigned short* __restrict__ xnT,
    const float* __restrict__ table, unsigned short* __restrict__ biasP) {
  __shared__ float red[4][32][2];
  __shared__ float gsh[512];
  __shared__ unsigned short obuf[32 * 520];
  int bid = blockIdx.x, tid = threadIdx.x;

  if (bid >= 640) {
    int base = ((bid - 640) * 256 + tid) * 8;    // 8M total / 8 per thread
    int h = base >> 20;
    int i = (base >> 10) & 1023;
    int j0 = base & 1023;
    int ib = i >> 5, il = i & 31;
    u16x8 outv;
    #pragma unroll
    for (int e = 0; e < 8; ++e) {
      int j = j0 + e;
      int dy = ib - (j >> 5) + 31;
      int dx = il - (j & 31) + 31;
      outv[e] = f2bf(table[h * 3969 + dy * 63 + dx]);
    }
    *(u16x8*)&biasP[base] = outv;
    return;
  }

  if (bid < 384) {
    int base = bid * 2048 + tid * 8;
    float sc = (base < 512 * CCH) ? (0.125f * LOG2E) : 1.0f;
    f32x4 v0 = *(const f32x4*)&wq[base];
    f32x4 v1 = *(const f32x4*)&wq[base + 4];
    u16x8 outv;
    #pragma unroll
    for (int e = 0; e < 4; ++e) outv[e] = f2bf(v0[e] * sc);
    #pragma unroll
    for (int e = 0; e < 4; ++e) outv[4 + e] = f2bf(v1[e] * sc);
    *(u16x8*)&wqb[base] = outv;
    if (base < CCH * CCH) {
      f32x4 w0v = *(const f32x4*)&wo[base];
      f32x4 w1v = *(const f32x4*)&wo[base + 4];
      u16x8 ov;
      #pragma unroll
      for (int e = 0; e < 4; ++e) ov[e] = f2bf(w0v[e]);
      #pragma unroll
      for (int e = 0; e < 4; ++e) ov[4 + e] = f2bf(w1v[e]);
      *(u16x8*)&wob[base] = ov;
    }
  } else {
    int blk = bid - 384;
    int b = blk >> 5, p0 = (blk & 31) * 32;
    int pl = tid & 31, wv = tid >> 6, cg = tid >> 5;
    gsh[tid] = gamma[tid];
    gsh[tid + 256] = gamma[tid + 256];
    const float* xp = x + (size_t)b * CCH * NPOS + p0 + pl;
    float vals[64];
    float s1 = 0.f, s2 = 0.f;
    #pragma unroll
    for (int j = 0; j < 64; ++j) {
      float v = xp[(size_t)(cg + 8 * j) * NPOS];
      vals[j] = v; s1 += v; s2 += v * v;
    }
    s1 += __shfl_xor(s1, 32, 64); s2 += __shfl_xor(s2, 32, 64);
    if ((tid & 63) < 32) { red[wv][pl][0] = s1; red[wv][pl][1] = s2; }
    __syncthreads();
    float t1 = 0.f, t2 = 0.f;
    #pragma unroll
    for (int w2i = 0; w2i < 4; ++w2i) { t1 += red[w2i][pl][0]; t2 += red[w2i][pl][1]; }
    float mean = t1 * (1.f / 512.f);
    float var = t2 * (1.f / 512.f) - mean * mean;
    float rstd = rsqrtf(var + EPS);
    #pragma unroll
    for (int j = 0; j < 64; ++j) {
      int c = cg + 8 * j;
      obuf[pl * 520 + c] = f2bf((vals[j] - mean) * rstd * gsh[c]);
    }
    __syncthreads();
    unsigned short* orow = xnT + ((size_t)b * NPOS + p0) * 512;
    #pragma unroll
    for (int i = 0; i < 8; ++i) {
      int c2 = tid + i * 256;
      int pp = c2 >> 6, ch = c2 & 63;
      *(u16x8*)&orow[(size_t)pp * 512 + ch * 8] = *(const u16x8*)&obuf[pp * 520 + ch * 8];
    }
  }
}

// ---------------- 2. CPB table with LDS-cached w1/w2 ----------------
__global__ __launch_bounds__(256) void cpb_kernel(
    const float* __restrict__ w0, const float* __restrict__ b0,
    const float* __restrict__ w1, const float* __restrict__ b1,
    const float* __restrict__ w2, const float* __restrict__ b2,
    float* __restrict__ table) {
  __shared__ float w1s[128 * 129];
  __shared__ float w2s[8 * 128];
  __shared__ float sh1[2][128];
  __shared__ float sh2[2][128];
  int tid = threadIdx.x;
  #pragma unroll
  for (int i = 0; i < 64; ++i) {
    int idx = i * 256 + tid;
    w1s[(idx >> 7) * 129 + (idx & 127)] = w1[idx];
  }
  #pragma unroll
  for (int i = 0; i < 4; ++i) {
    int idx = i * 256 + tid;
    w2s[idx] = w2[idx];
  }
  int sub = tid >> 7, t = tid & 127;
  float w00 = w0[t * 2 + 0], w01 = w0[t * 2 + 1], bb0 = b0[t], bb1 = b1[t];
  int hh = t >> 4, k16 = t & 15;
  float b2h = b2[hh];
  __syncthreads();

  #pragma unroll 1
  for (int pass = 0; pass < 8; ++pass) {
    int d0 = (blockIdx.x * 8 + pass) * 2 + sub;
    bool ok = d0 < 3969;
    int d0c = ok ? d0 : 0;
    int dy = d0c / 63 - 31, dx = d0c % 63 - 31;
    float r0 = (dy > 0 ? 1.f : (dy < 0 ? -1.f : 0.f)) * logf(fabsf((float)dy) + 1.f);
    float r1 = (dx > 0 ? 1.f : (dx < 0 ? -1.f : 0.f)) * logf(fabsf((float)dx) + 1.f);
    float h0 = r0 * w00 + r1 * w01 + bb0;
    sh1[sub][t] = (h0 >= 0.f) ? h0 : 0.1f * h0;
    __syncthreads();
    float a = bb1;
    #pragma unroll 8
    for (int c = 0; c < 128; ++c) a += sh1[sub][c] * w1s[t * 129 + c];
    sh2[sub][t] = (a >= 0.f) ? a : 0.1f * a;
    __syncthreads();
    float o = 0.f;
    #pragma unroll
    for (int c = 0; c < 8; ++c) o += sh2[sub][k16 * 8 + c] * w2s[hh * 128 + k16 * 8 + c];
    #pragma unroll
    for (int mm = 1; mm < 16; mm <<= 1) o += __shfl_xor(o, mm, 64);
    if (k16 == 0 && ok) table[hh * 3969 + d0] = (o + b2h) * LOG2E;
    __syncthreads();
  }
}

// ---------------- 3. qkv GEMM: BK=32 TRIPLE-buffered counted-vmcnt pipeline ----------------
__global__ __launch_bounds__(256) void gemm_qkv(const unsigned short* __restrict__ Ag,
                                                const unsigned short* __restrict__ Bg,
                                                unsigned short* __restrict__ qT,
                                                unsigned short* __restrict__ kT,
                                                unsigned short* __restrict__ vB) {
  __shared__ unsigned short smem[24576];
  int tid = threadIdx.x;
  int by = blockIdx.y;
  int m0 = by * 128, nn0 = blockIdx.x * 128;
  int wave = tid >> 6, lane = tid & 63;
  int wm = wave >> 1, wn = wave & 1;
  int l16 = lane & 15, lh = lane >> 4;
  int r4 = lane >> 2, c4 = lane & 3;
  int csw = ((c4 ^ (r4 & 3) ^ ((lane >> 4) & 3))) << 3;
  f32x4 acc[4][4];
  #pragma unroll
  for (int it = 0; it < 4; ++it)
    #pragma unroll
    for (int jt = 0; jt < 4; ++jt) acc[it][jt] = (f32x4){0.f, 0.f, 0.f, 0.f};

  #define GSTAGE(bsel, k0) do {                                                               \
    _Pragma("unroll")                                                                         \
    for (int i_ = 0; i_ < 2; ++i_) {                                                          \
      int grp_ = wave * 2 + i_;                                                               \
      int row_ = grp_ * 16 + r4;                                                              \
      gload16(&Ag[(size_t)(m0 + row_) * 512 + (k0) + csw], smem + (bsel) * 4096 + grp_ * 512);\
      gload16(&Bg[(size_t)(nn0 + row_) * 512 + (k0) + csw],                                   \
              smem + 12288 + (bsel) * 4096 + grp_ * 512);                                     \
    }                                                                                         \
  } while (0)

  GSTAGE(0, 0);
  GSTAGE(1, 32);
  asm volatile("s_waitcnt vmcnt(4)" ::: "memory");
  __builtin_amdgcn_s_barrier();
  int cur = 0;
  #pragma unroll 1
  for (int k = 0; k < 16; ++k) {
    int stg = (cur == 0) ? 2 : cur - 1;
    if (k < 14) GSTAGE(stg, (k + 2) * 32);
    const unsigned short* As = smem + cur * 4096;
    const unsigned short* Bs = smem + 12288 + cur * 4096;
    bf16x8 a[4], b[4];
    #pragma unroll
    for (int it = 0; it < 4; ++it) a[it] = *(const bf16x8*)&As[sw32(wm * 64 + it * 16 + l16, lh)];
    #pragma unroll
    for (int jt = 0; jt < 4; ++jt) b[jt] = *(const bf16x8*)&Bs[sw32(wn * 64 + jt * 16 + l16, lh)];
    __builtin_amdgcn_s_setprio(1);
    #pragma unroll
    for (int it = 0; it < 4; ++it)
      #pragma unroll
      for (int jt = 0; jt < 4; ++jt)
        acc[it][jt] = __builtin_amdgcn_mfma_f32_16x16x32_bf16(a[it], b[jt], acc[it][jt], 0, 0, 0);
    __builtin_amdgcn_s_setprio(0);
    if (k < 14) CBAR(4); else CBAR(0);
    cur = (cur == 2) ? 0 : cur + 1;
  }

  // ---- LDS-bounced coalesced epilogue ----
  int sel = by >> 2;
  int hh0 = (by & 3) * 2;
  int bb = nn0 >> 10, p0 = nn0 & 1023;
  unsigned short* Cs = smem;
  if (sel < 2) {
    #pragma unroll
    for (int it = 0; it < 4; ++it)
      #pragma unroll
      for (int jt = 0; jt < 4; ++jt) {
        int nnl = wn * 64 + jt * 16 + l16;
        int mb = wm * 64 + it * 16 + lh * 4;
        #pragma unroll
        for (int r = 0; r < 4; ++r)
          Cs[nnl * 128 + ((mb + r) ^ ((nnl & 7) << 4))] = f2bf(acc[it][jt][r]);
      }
    __syncthreads();
    unsigned short* dst = (sel == 0) ? qT : kT;
    #pragma unroll
    for (int i = 0; i < 8; ++i) {
      int c = tid + i * 256;
      int hl = c >> 10, p = (c >> 3) & 127, ch = c & 7;
      int mb = hl * 64 + ch * 8;
      u16x8 val = *(u16x8*)&Cs[p * 128 + (mb ^ ((p & 7) << 4))];
      int bh = bb * 8 + hh0 + hl;
      *(u16x8*)&dst[((size_t)bh * 1024 + p0 + p) * 64 + ch * 8] = val;
    }
  } else {
    #pragma unroll
    for (int it = 0; it < 4; ++it)
      #pragma unroll
      for (int jt = 0; jt < 4; ++jt) {
        int nnl = wn * 64 + jt * 16 + l16;
        int mb = wm * 64 + it * 16 + lh * 4;
        #pragma unroll
        for (int r = 0; r < 4; ++r)
          Cs[(mb + r) * 128 + (nnl ^ (((mb + r) & 7) << 4))] = f2bf(acc[it][jt][r]);
      }
    __syncthreads();
    #pragma unroll
    for (int i = 0; i < 8; ++i) {
      int c = tid + i * 256;
      int mloc = c >> 4, ch = c & 15;
      u16x8 val = *(u16x8*)&Cs[mloc * 128 + ((ch * 8) ^ ((mloc & 7) << 4))];
      int d = mloc & 63, hl = mloc >> 6;
      int bh = bb * 8 + hh0 + hl;
      *(u16x8*)&vB[((size_t)bh * 64 + d) * 1024 + p0 + ch * 8] = val;
    }
  }
}

// ---------------- 4. out GEMM: 64x128 tiles, TRIPLE-buffered counted-vmcnt ----------------
__global__ __launch_bounds__(256) void gemm_out(const unsigned short* __restrict__ Ag,
                                                const unsigned short* __restrict__ Bg,
                                                const float* __restrict__ xres,
                                                float* __restrict__ yout) {
  __shared__ unsigned short smem[18432];
  int tid = threadIdx.x;
  int m0 = blockIdx.y * 64, nn0 = blockIdx.x * 128;
  int wave = tid >> 6, lane = tid & 63;
  int wm = wave >> 1, wn = wave & 1;
  int l16 = lane & 15, lh = lane >> 4;
  int r4 = lane >> 2, c4 = lane & 3;
  int csw = ((c4 ^ (r4 & 3) ^ ((lane >> 4) & 3))) << 3;
  f32x4 acc[2][4];
  #pragma unroll
  for (int it = 0; it < 2; ++it)
    #pragma unroll
    for (int jt = 0; jt < 4; ++jt) acc[it][jt] = (f32x4){0.f, 0.f, 0.f, 0.f};

  #define OSTAGE(bsel, k0) do {                                                               \
    {                                                                                         \
      int row_ = wave * 16 + r4;                                                              \
      gload16(&Ag[(size_t)(m0 + row_) * 512 + (k0) + csw],                                    \
              smem + (bsel) * 2048 + wave * 512);                                             \
    }                                                                                         \
    _Pragma("unroll")                                                                         \
    for (int i_ = 0; i_ < 2; ++i_) {                                                          \
      int grp_ = wave * 2 + i_;                                                               \
      int row_ = grp_ * 16 + r4;                                                              \
      gload16(&Bg[(size_t)(nn0 + row_) * 512 + (k0) + csw],                                   \
              smem + 6144 + (bsel) * 4096 + grp_ * 512);                                      \
    }                                                                                         \
  } while (0)

  OSTAGE(0, 0);
  OSTAGE(1, 32);
  asm volatile("s_waitcnt vmcnt(3)" ::: "memory");
  __builtin_amdgcn_s_barrier();
  int cur = 0;
  #pragma unroll 1
  for (int k = 0; k < 16; ++k) {
    int stg = (cur == 0) ? 2 : cur - 1;
    if (k < 14) OSTAGE(stg, (k + 2) * 32);
    const unsigned short* As = smem + cur * 2048;
    const unsigned short* Bs = smem + 6144 + cur * 4096;
    bf16x8 a[2], b[4];
    #pragma unroll
    for (int it = 0; it < 2; ++it) a[it] = *(const bf16x8*)&As[sw32(wm * 32 + it * 16 + l16, lh)];
    #pragma unroll
    for (int jt = 0; jt < 4; ++jt) b[jt] = *(const bf16x8*)&Bs[sw32(wn * 64 + jt * 16 + l16, lh)];
    __builtin_amdgcn_s_setprio(1);
    #pragma unroll
    for (int it = 0; it < 2; ++it)
      #pragma unroll
      for (int jt = 0; jt < 4; ++jt)
        acc[it][jt] = __builtin_amdgcn_mfma_f32_16x16x32_bf16(a[it], b[jt], acc[it][jt], 0, 0, 0);
    __builtin_amdgcn_s_setprio(0);
    if (k < 14) CBAR(3); else CBAR(0);
    cur = (cur == 2) ? 0 : cur + 1;
  }

  #pragma unroll
  for (int it = 0; it < 2; ++it) {
    int mbase = m0 + wm * 32 + it * 16 + lh * 4;
    #pragma unroll
    for (int jt = 0; jt < 4; ++jt) {
      int nn = nn0 + wn * 64 + jt * 16 + l16;
      int bb = nn >> 10, p = nn & 1023;
      #pragma unroll
      for (int r = 0; r < 4; ++r) {
        size_t addr = ((size_t)bb * 512 + mbase + r) * 1024 + p;
        yout[addr] = acc[it][jt][r] + xres[addr];
      }
    }
  }
}

// ---------------- 5. flash attention: 8 waves / 128 q-rows, TRIPLE-buffered K/V ----------------
// (r21 proven version) Consecutive-j fragments; bias double-buffered in registers one tile
// ahead; counted-vmcnt barriers with exact tail ledger.
__global__ __launch_bounds__(512) void attn_kernel(const unsigned short* __restrict__ qT,
                                                   const unsigned short* __restrict__ kT,
                                                   const unsigned short* __restrict__ vB,
                                                   const unsigned short* __restrict__ biasP,
                                                   unsigned short* __restrict__ attnout) {
  __shared__ unsigned short Kbuf[3][64 * 64];
  __shared__ unsigned short Vbuf[3][64 * 64];
  __shared__ unsigned short Ps[8][16 * 64];
  int tid = threadIdx.x;
  int bh = blockIdx.x;               // bh-fastest: XCD = bh%8
  int i0 = blockIdx.y * 128;
  int hh = bh & 7, bb = bh >> 3;
  int w = tid >> 6, lane = tid & 63, l16 = lane & 15, lh = lane >> 4;
  int rsub = lane >> 3, csub = lane & 7;
  int scswV = (csub ^ rsub) * 8;                        // V source pre-swizzle (row&7)
  int scswK = (csub ^ ((w * 2 + (rsub >> 2)) & 7)) * 8; // K source pre-swizzle (row>>2)&7

  const unsigned short* kbase = kT + (size_t)bh * NPOS * 64;
  const unsigned short* vbase = vB + (size_t)bh * 64 * NPOS;
  const unsigned short* bptr  = biasP + ((size_t)hh * 1024 + i0 + w * 16) * 1024 + l16 * 4;

  // Q fragments in registers (one q-row per lane)
  int qrow = i0 + w * 16 + l16;
  const unsigned short* qb = qT + ((size_t)bh * NPOS + qrow) * 64 + lh * 8;
  bf16x8 qreg[2];
  qreg[0] = *(const bf16x8*)&qb[0];
  qreg[1] = *(const bf16x8*)&qb[32];

  f32x4 o[5];                        // 0..3 output d-fragments, 4 = softmax denominator
  #pragma unroll
  for (int dt = 0; dt < 5; ++dt) o[dt] = (f32x4){0.f, 0.f, 0.f, 0.f};

  bf16x8 ones;
  {
    u16x8 tmp = {0x3F80, 0x3F80, 0x3F80, 0x3F80, 0x3F80, 0x3F80, 0x3F80, 0x3F80};
    ones = __builtin_bit_cast(bf16x8, tmp);
  }

  // stage tile jj: each of 8 waves stages 1 K-group + 1 V-group (2 vmem loads/thread)
  #define STAGE(Kd, Vd, jj) do {                                                        \
    gload16(&kbase[(size_t)((jj) + w * 8 + rsub) * 64 + scswK], &(Kd)[w * 512]);        \
    gload16(&vbase[(size_t)(w * 8 + rsub) * 1024 + (jj) + scswV], &(Vd)[w * 512]);      \
  } while (0)

  // prologue: stage tile0; bias(0) into regs; stage tile1.
  STAGE(Kbuf[0], Vbuf[0], 0);
  u16x4 bvc[4];
  #pragma unroll
  for (int r = 0; r < 4; ++r) bvc[r] = *(const u16x4*)&bptr[(lh * 4 + r) * 1024];
  STAGE(Kbuf[1], Vbuf[1], 64);
  asm volatile("s_waitcnt vmcnt(6)" ::: "memory");
  __builtin_amdgcn_s_barrier();
  int cur = 0;

  #pragma unroll 1
  for (int t = 0; t < 16; ++t) {
    int j0 = t * 64;

    // bias(t+1) prefetch FIRST (older than staging in the vmcnt FIFO)
    u16x4 bvn[4];
    if (t < 15) {
      #pragma unroll
      for (int r = 0; r < 4; ++r) bvn[r] = *(const u16x4*)&bptr[(lh * 4 + r) * 1024 + j0 + 64];
    }

    int stg = (cur == 0) ? 2 : cur - 1;              // (cur+2)%3
    if (t < 14) STAGE(Kbuf[stg], Vbuf[stg], j0 + 128);

    const unsigned short* Ks = Kbuf[cur];
    const unsigned short* Vs = Vbuf[cur];

    // ---- QK^T: s[jt] holds score for j = l16*4 + jt ----
    f32x4 s[4];
    #pragma unroll
    for (int jt = 0; jt < 4; ++jt) s[jt] = (f32x4){0.f, 0.f, 0.f, 0.f};
    __builtin_amdgcn_s_setprio(1);
    #pragma unroll
    for (int ks = 0; ks < 2; ++ks) {
      int koff = ks * 32 + lh * 8;
      #pragma unroll
      for (int jt = 0; jt < 4; ++jt) {
        bf16x8 bk = *(const bf16x8*)&Ks[swk(l16 * 4 + jt, koff)];
        s[jt] = __builtin_amdgcn_mfma_f32_16x16x32_bf16(qreg[ks], bk, s[jt], 0, 0, 0);
      }
    }
    __builtin_amdgcn_s_setprio(0);

    // ---- softmax numerator: P = exp2(s + bias(t) from regs); ONE b64 store per row ----
    #pragma unroll
    for (int r = 0; r < 4; ++r) {
      int rloc = lh * 4 + r;
      u16x4 pq;
      #pragma unroll
      for (int jt = 0; jt < 4; ++jt)
        pq[jt] = f2bf(__builtin_amdgcn_exp2f(s[jt][r] + bf2f(bvc[r][jt])));
      *(u16x4*)&Ps[w][sw(rloc, l16 * 4)] = pq;
    }

    // ---- PV (Ps wave-private: no barrier). o[4] accumulates the denominator ----
    __builtin_amdgcn_s_setprio(1);
    #pragma unroll
    for (int js = 0; js < 2; ++js) {
      int koff = js * 32 + lh * 8;
      bf16x8 pa = *(const bf16x8*)&Ps[w][sw(l16, koff)];
      #pragma unroll
      for (int dt = 0; dt < 4; ++dt) {
        bf16x8 vb = *(const bf16x8*)&Vs[sw(dt * 16 + l16, koff)];
        o[dt] = __builtin_amdgcn_mfma_f32_16x16x32_bf16(pa, vb, o[dt], 0, 0, 0);
      }
      o[4] = __builtin_amdgcn_mfma_f32_16x16x32_bf16(pa, ones, o[4], 0, 0, 0);
    }
    __builtin_amdgcn_s_setprio(0);

    // rotate bias regs (read of bvn forces its retirement; staging stays in flight)
    if (t < 15) {
      #pragma unroll
      for (int r = 0; r < 4; ++r) bvc[r] = bvn[r];
    }

    if (t < 14) CBAR(6);
    else if (t == 14) CBAR(4);
    else CBAR(0);
    cur = (cur == 2) ? 0 : cur + 1;
  }

  #pragma unroll
  for (int r = 0; r < 4; ++r) {
    float inv = 1.f / o[4][r];
    int gi = i0 + w * 16 + lh * 4 + r;
    #pragma unroll
    for (int dt = 0; dt < 4; ++dt)
      attnout[((size_t)bb * 1024 + gi) * 512 + hh * 64 + dt * 16 + l16] = f2bf(o[dt][r] * inv);
  }
}

extern "C" void kernel_launch(void* const* d_in, const int* in_sizes, int n_in,
                              void* d_out, int out_size, void* d_ws, size_t ws_size,
                              hipStream_t stream) {
  const float* x     = (const float*)d_in[0];
  const float* gamma = (const float*)d_in[1];
  const float* w_qkv = (const float*)d_in[2];
  const float* w_out = (const float*)d_in[3];
  const float* cw0   = (const float*)d_in[4];
  const float* cb0   = (const float*)d_in[5];
  const float* cw1   = (const float*)d_in[6];
  const float* cb1   = (const float*)d_in[7];
  const float* cw2   = (const float*)d_in[8];
  const float* cb2   = (const float*)d_in[9];
  float* out = (float*)d_out;

  char* ws = (char*)d_ws;
  unsigned short* xnT   = (unsigned short*)(ws + 0);          // 8 MB
  unsigned short* wqb   = (unsigned short*)(ws + 8388608);    // 1.5 MB
  unsigned short* wob   = (unsigned short*)(ws + 9961472);    // 0.5 MB
  unsigned short* qT    = (unsigned short*)(ws + 10485760);   // 8 MB
  unsigned short* kT    = (unsigned short*)(ws + 18874368);   // 8 MB
  unsigned short* vB    = (unsigned short*)(ws + 27262976);   // 8 MB
  float*          table = (float*)(ws + 35651584);            // 128 KB
  unsigned short* biasP = (unsigned short*)(ws + 35782656);   // 16 MB
  unsigned short* aout  = (unsigned short*)(ws + 52559872);   // 8 MB

  cpb_kernel<<<256, 256, 0, stream>>>(cw0, cb0, cw1, cb1, cw2, cb2, table);
  setup_kernel<<<4736, 256, 0, stream>>>(w_qkv, w_out, wqb, wob, x, gamma, xnT, table, biasP);
  gemm_qkv<<<dim3(64, 12), 256, 0, stream>>>(wqb, xnT, qT, kT, vB);
  attn_kernel<<<dim3(64, 8), 512, 0, stream>>>(qT, kT, vB, biasP, aout);
  gemm_out<<<dim3(64, 8), 256, 0, stream>>>(wob, aout, x, out);
}